// Round 8
// baseline (253.824 us; speedup 1.0000x reference)
//
#include <hip/hip_runtime.h>
#include <hip/hip_bf16.h>

// Problem constants
#define B_      1024
#define CIN     9
#define T0_     2048
#define C1_     16
#define C2_     32
#define RT_     512
#define NNODES  (B_ * RT_)     // 524288
#define HID_    128
#define OUTF_   64

typedef __attribute__((ext_vector_type(8))) __bf16 bf16x8;
typedef __attribute__((ext_vector_type(4))) float f32x4;
typedef __attribute__((ext_vector_type(8))) unsigned short us8;

// ---------- helpers ----------
__device__ __forceinline__ float bf2f(unsigned short u) {
    union { unsigned int i; float f; } c; c.i = ((unsigned int)u) << 16; return c.f;
}
// round-half-up bf16 (2 ops)
__device__ __forceinline__ unsigned short f2bf1(float f) {
    union { float f; unsigned int i; } c; c.f = f;
    return (unsigned short)((c.i + 0x8000u) >> 16);
}
// packed pair: low short = bf16(lo), high short = bf16(hi); 2 adds + 1 v_perm
__device__ __forceinline__ unsigned int f2bf2(float lo, float hi) {
    union { float f; unsigned int i; } a, b; a.f = lo; b.f = hi;
    return __builtin_amdgcn_perm(b.i + 0x8000u, a.i + 0x8000u, 0x07060302u);
}
__device__ __forceinline__ float dinv_of(int r) {
    return (r == 0 || r == RT_ - 1) ? 0.70710678118f : 0.57735026919f;
}

// ---------- kernel R: repack all weights into bf16 MFMA fragment order (32 blocks) ----------
__global__ __launch_bounds__(256) void repack_w(
    const float* __restrict__ W1g, const float* __restrict__ W2g,
    const float* __restrict__ Wc1g, const float* __restrict__ Wc2g,
    unsigned short* __restrict__ Wb1, unsigned short* __restrict__ Wb2,
    unsigned short* __restrict__ Wc1, unsigned short* __restrict__ Wc2)
{
    const int tid = threadIdx.x;
    const int bid = blockIdx.x;
    if (bid < 8) {                                     // W1: 4096 elems, 512/block
        for (int i = tid; i < 512; i += 256) {
            int s = bid * 512 + i;
            int k = s >> 7, f = s & 127;
            int lane = ((k >> 3) << 4) + (f & 15);
            int e = (((f >> 4) * 64) + lane) * 8 + (k & 7);
            Wb1[e] = f2bf1(W1g[s]);
        }
    } else if (bid < 24) {                             // W2: 16384 elems, 1024/block
        for (int i = tid; i < 1024; i += 256) {
            int s = (bid - 8) * 1024 + i;
            int k = s >> 7, f = s & 127;
            int ks = k >> 5, lane = (((k >> 3) & 3) << 4) + (f & 15);
            int e = ((ks * 8 + (f >> 4)) * 64 + lane) * 8 + (k & 7);
            Wb2[e] = f2bf1(W2g[s]);
        }
    } else if (bid < 28) {                             // Wc1: 1536 elems, 384/block
        for (int i = tid; i < 384; i += 256) {
            int e = (bid - 24) * 384 + i;
            int j = e & 7, lane = (e >> 3) & 63, ks = e >> 9;
            int kk = ks * 32 + (lane >> 4) * 8 + j;
            int k = kk >> 4, ci = kk & 15, co = lane & 15;
            Wc1[e] = (k < 5 && ci < CIN) ? f2bf1(Wc1g[(co * CIN + ci) * 5 + k]) : 0;
        }
    } else {                                           // Wc2: 3072 elems, 768/block
        for (int i = tid; i < 768; i += 256) {
            int e = (bid - 28) * 768 + i;
            int j = e & 7, lane = (e >> 3) & 63, nt = (e >> 9) & 1, ks = e >> 10;
            int kk = ks * 32 + (lane >> 4) * 8 + j;
            int k = kk >> 4, ci = kk & 15, co = nt * 16 + (lane & 15);
            Wc2[e] = (k < 5) ? f2bf1(Wc2g[(co * C1_ + ci) * 5 + k]) : 0;
        }
    }
}

// ---------- MEGAKERNEL ----------
// R18: barrier-free wave-private pipeline. Each wave owns ONE quarter (32
// nodes) end-to-end through a private 13,440-B LDS arena: stage x-slice ->
// conv1 -> conv2 -> gcn1-agg -> (per 16-node half: gcn1-matmul -> gcn2-agg
// stencil -> gcn2-matmul + reduce). Work totals match the old block-coop
// scheme (F: 64 elems/lane, G: 64 MFMA/wave in BOTH); costs are ~20% conv halo
// + L2-hot weight reloads. __syncthreads: 13 -> 1 (final reduce only).
// Rationale: R11/R14/R17 all latency-bound at ~72% issue with barrier-aligned
// phase chains; removing VALU (R17) didn't help, so remove the serialization.
//
// Per-wave arena (shorts, base = wave*6720):
//   xs  [0,4608)    192 rows * 24   A..B
//   y1  [4608,6720)  88 rows * 24   B..C
//   y2  [2432,3872)  36 rows * 40   C..D
//   As1 [0,1920)     48 rows * 40   D..E (rows 34..47 stale-garbage, masked)
//   Hq  [1920,4368)  18 rows * 136  E..F (per half)
//   A2q [4368,6544)  16 rows * 136  F..G (per half)
//   scratch [4608,4864) 128 floats  after G (A2q/y1 dead)
__global__ __launch_bounds__(256, 3) void mega(
    const float* __restrict__ x,             // [B][9][2048] fp32
    const unsigned short* __restrict__ Wc1,  // conv1 B-frags
    const unsigned short* __restrict__ Wc2,  // conv2 B-frags
    const unsigned short* __restrict__ Wb1,  // gcn1 A-frags (W1^T)
    const unsigned short* __restrict__ Wb2,  // gcn2 B-frags
    const float* __restrict__ c1b, const float* __restrict__ c2b,
    const float* __restrict__ g1b, const float* __restrict__ g2b,
    float* __restrict__ partials)            // [B][4][128] fp32
{
    __shared__ __align__(16) unsigned char lds[53760];

    const int tid = threadIdx.x;
    const int b = blockIdx.x >> 2;
    const int r0 = (blockIdx.x & 3) * 128;
    const int lane = tid & 63, wave = tid >> 6;
    const int m = lane & 15, q = lane >> 4;
    const int w32 = wave * 32;               // this wave's node offset in block

    unsigned short* arena = (unsigned short*)lds + wave * 6720;
    unsigned short* xs  = arena;
    unsigned short* y1  = arena + 4608;
    unsigned short* y2  = arena + 2432;
    unsigned short* As1 = arena;
    unsigned short* Hq  = arena + 1920;
    unsigned short* A2q = arena + 4368;

    // conv1 fragments
    bf16x8 wfB[3];
    #pragma unroll
    for (int ks = 0; ks < 3; ks++) wfB[ks] = *(const bf16x8*)(Wc1 + (ks * 64 + lane) * 8);

    // ---- A (per-wave): stage xs rows 0..191; xt = 4r0-14+128w + s. All rows
    //      valid-or-zero so every downstream MFMA read is clean.
    {
        const float* xb = x + (size_t)b * CIN * T0_;
        const int xbase = 4 * r0 - 14 + 128 * wave;
        #pragma unroll
        for (int i = 0; i < 3; i++) {
            const int s = lane + 64 * i;
            const int xt = xbase + s;
            union { us8 v; unsigned int u[4]; } o0, o1;
            if (xt >= 0 && xt < T0_) {
                float xv[9];
                #pragma unroll
                for (int ci = 0; ci < 9; ci++) xv[ci] = xb[ci * T0_ + xt];
                o0.u[0] = f2bf2(xv[0], xv[1]); o0.u[1] = f2bf2(xv[2], xv[3]);
                o0.u[2] = f2bf2(xv[4], xv[5]); o0.u[3] = f2bf2(xv[6], xv[7]);
                o1.u[0] = f2bf2(xv[8], 0.f);   o1.u[1] = o1.u[2] = o1.u[3] = 0;
            } else {
                o0.u[0] = o0.u[1] = o0.u[2] = o0.u[3] = 0;
                o1.u[0] = o1.u[1] = o1.u[2] = o1.u[3] = 0;
            }
            *(us8*)(xs + s * 24) = o0.v;
            *(us8*)(xs + s * 24 + 8) = o1.v;
        }
    }

    // ---- B (per-wave): conv1+relu+pool -> y1 rows 0..87 (t1 = 2r0-6+64w+p)
    {
        const float bv = c1b[m];
        const int t1base = 2 * r0 - 6 + 64 * wave;
        for (int mt = 0; mt < 11; mt++) {
            f32x4 acc = {};
            #pragma unroll
            for (int ks = 0; ks < 3; ks++) {
                const int row = mt * 16 + m + ks * 2 + (q >> 1);
                const bf16x8 af = *(const bf16x8*)(xs + row * 24 + (q & 1) * 8);
                acc = __builtin_amdgcn_mfma_f32_16x16x32_bf16(af, wfB[ks], acc, 0, 0, 0);
            }
            const int prow = mt * 8 + q * 2;        // <= 87
            const int t1a = t1base + prow, t1b = t1a + 1;
            const float p0 = fmaxf(fmaxf(acc[0], acc[1]) + bv, 0.f);
            const float p1 = fmaxf(fmaxf(acc[2], acc[3]) + bv, 0.f);
            y1[prow * 24 + m]       = (t1a >= 0 && t1a < 1024) ? f2bf1(p0) : (unsigned short)0;
            y1[(prow + 1) * 24 + m] = (t1b >= 0 && t1b < 1024) ? f2bf1(p1) : (unsigned short)0;
        }
    }

    // ---- C (per-wave): conv2+relu+pool -> y2 rows 0..35 (node r0-2+32w+n)
    {
        bf16x8 wfC[3][2];
        #pragma unroll
        for (int ks = 0; ks < 3; ks++)
            #pragma unroll
            for (int nt = 0; nt < 2; nt++)
                wfC[ks][nt] = *(const bf16x8*)(Wc2 + ((ks * 2 + nt) * 64 + lane) * 8);
        const float bv0 = c2b[m], bv1 = c2b[16 + m];
        for (int mt = 0; mt < 5; mt++) {
            f32x4 a0 = {}, a1 = {};
            #pragma unroll
            for (int ks = 0; ks < 3; ks++) {
                const int row = mt * 16 + m + ks * 2 + (q >> 1);
                const bf16x8 af = *(const bf16x8*)(y1 + row * 24 + (q & 1) * 8);
                a0 = __builtin_amdgcn_mfma_f32_16x16x32_bf16(af, wfC[ks][0], a0, 0, 0, 0);
                a1 = __builtin_amdgcn_mfma_f32_16x16x32_bf16(af, wfC[ks][1], a1, 0, 0, 0);
            }
            const int nrow = mt * 8 + q * 2;
            if (nrow < 36) {
                y2[nrow * 40 + m]      = f2bf1(fmaxf(fmaxf(a0[0], a0[1]) + bv0, 0.f));
                y2[nrow * 40 + 16 + m] = f2bf1(fmaxf(fmaxf(a1[0], a1[1]) + bv1, 0.f));
            }
            if (nrow + 1 < 36) {
                y2[(nrow + 1) * 40 + m]      = f2bf1(fmaxf(fmaxf(a0[2], a0[3]) + bv0, 0.f));
                y2[(nrow + 1) * 40 + 16 + m] = f2bf1(fmaxf(fmaxf(a1[2], a1[3]) + bv1, 0.f));
            }
        }
    }

    // ---- D (per-wave): gcn1 aggregation -> As1 rows 0..33 (node r0-1+32w+j)
    for (int s2 = lane; s2 < 68; s2 += 64) {
        const int j = s2 >> 1, fh = (s2 & 1) * 16;
        unsigned short* dst = As1 + j * 40 + fh;
        const int r = r0 + w32 - 1 + j;
        union { us8 v; unsigned int u[4]; } o0, o1;
        if (r < 0 || r >= RT_) {
            o0.u[0] = o0.u[1] = o0.u[2] = o0.u[3] = 0;
            o1.u[0] = o1.u[1] = o1.u[2] = o1.u[3] = 0;
        } else {
            const float dm = dinv_of(r), cm = dm * dm;
            const unsigned short* Yc = y2 + (j + 1) * 40 + fh;
            us8 c0 = *(const us8*)(Yc), c1 = *(const us8*)(Yc + 8);
            float v[16];
            #pragma unroll
            for (int jj = 0; jj < 8; jj++) { v[jj] = cm * bf2f(c0[jj]); v[8 + jj] = cm * bf2f(c1[jj]); }
            if (r > 0) {
                const float cl = dm * dinv_of(r - 1);
                us8 a0 = *(const us8*)(Yc - 40), a1 = *(const us8*)(Yc - 32);
                #pragma unroll
                for (int jj = 0; jj < 8; jj++) { v[jj] += cl * bf2f(a0[jj]); v[8 + jj] += cl * bf2f(a1[jj]); }
            }
            if (r < RT_ - 1) {
                const float cr = dm * dinv_of(r + 1);
                us8 a0 = *(const us8*)(Yc + 40), a1 = *(const us8*)(Yc + 48);
                #pragma unroll
                for (int jj = 0; jj < 8; jj++) { v[jj] += cr * bf2f(a0[jj]); v[8 + jj] += cr * bf2f(a1[jj]); }
            }
            #pragma unroll
            for (int i2 = 0; i2 < 4; i2++) {
                o0.u[i2] = f2bf2(v[2 * i2], v[2 * i2 + 1]);
                o1.u[i2] = f2bf2(v[8 + 2 * i2], v[9 + 2 * i2]);
            }
        }
        *(us8*)dst = o0.v; *(us8*)(dst + 8) = o1.v;
    }

    // gcn2 biases (L2-resident)
    float bias_j[8];
    #pragma unroll
    for (int j = 0; j < 8; j++) bias_j[j] = g2b[j * 16 + m];
    float s_acc[8] = {0.f, 0.f, 0.f, 0.f, 0.f, 0.f, 0.f, 0.f};

    const f32x4 zz = {};

    // ---- tail: two 16-node halves per wave, no barriers
    #pragma unroll 1
    for (int hs = 0; hs < 2; hs++) {
        // E half: Hq rows 0..17 <-> nodes r0+32w-1+hs*16+h, all 128 feats.
        // B-frag As1 rows hs*16 + nt*16 + m; garbage rows >=34 land only in
        // masked Hq rows (hrow = nt*16+m >= 18).
        #pragma unroll 2
        for (int ft = 0; ft < 8; ft++) {
            const bf16x8 wf = *(const bf16x8*)(Wb1 + ((size_t)(ft * 64 + lane)) * 8);
            const float4 bvf = *(const float4*)&g1b[ft * 16 + q * 4];
            #pragma unroll
            for (int nt = 0; nt < 2; nt++) {
                const bf16x8 bfr = *(const bf16x8*)(As1 + (hs * 16 + nt * 16 + m) * 40 + q * 8);
                f32x4 o = __builtin_amdgcn_mfma_f32_16x16x32_bf16(wf, bfr, zz, 0, 0, 0);
                const int hrow = nt * 16 + m;
                if (hrow < 18) {
                    union { ushort4 s; unsigned int u[2]; } w0;
                    w0.u[0] = f2bf2(fmaxf(o[0] + bvf.x, 0.f), fmaxf(o[1] + bvf.y, 0.f));
                    w0.u[1] = f2bf2(fmaxf(o[2] + bvf.z, 0.f), fmaxf(o[3] + bvf.w, 0.f));
                    *(ushort4*)(Hq + hrow * 136 + ft * 16 + q * 4) = w0.s;
                }
            }
        }

        // F half: stencil Hq -> A2q (16 nodes x 128 feats; 2 units/lane)
        #pragma unroll
        for (int u = 0; u < 2; u++) {
            const int idx = lane + 64 * u;          // 0..127
            const int jl = idx >> 3, fh = (idx & 7) * 16;
            const int r = r0 + w32 + hs * 16 + jl;
            const float dm = dinv_of(r), cm = dm * dm;
            const float cl = (r > 0) ? dm * dinv_of(r - 1) : 0.f;
            const float cr = (r < RT_ - 1) ? dm * dinv_of(r + 1) : 0.f;
            const unsigned short* Hl = Hq + jl * 136 + fh;
            const unsigned short* Hc = Hl + 136;
            const unsigned short* Hr = Hc + 136;
            unsigned short* dst = A2q + jl * 136 + fh;
            #pragma unroll
            for (int c = 0; c < 2; c++) {
                us8 cc = *(const us8*)(Hc + c * 8);
                us8 ll = *(const us8*)(Hl + c * 8);
                us8 rr = *(const us8*)(Hr + c * 8);
                float v[8];
                #pragma unroll
                for (int e = 0; e < 8; e++)
                    v[e] = cm * bf2f(cc[e]) + cl * bf2f(ll[e]) + cr * bf2f(rr[e]);
                union { us8 v; unsigned int u[4]; } o;
                #pragma unroll
                for (int i2 = 0; i2 < 4; i2++) o.u[i2] = f2bf2(v[2 * i2], v[2 * i2 + 1]);
                *(us8*)(dst + c * 8) = o.v;
            }
        }

        // G half: gcn2 MFMA over all 8 out-feat tiles; sum over nodes into s_acc
        {
            bf16x8 ga[4];
            #pragma unroll
            for (int ks = 0; ks < 4; ks++)
                ga[ks] = *(const bf16x8*)(A2q + m * 136 + ks * 32 + q * 8);
            #pragma unroll
            for (int j = 0; j < 8; j++) {
                f32x4 P = {};
                #pragma unroll
                for (int ks = 0; ks < 4; ks++) {
                    const bf16x8 bwf = *(const bf16x8*)(Wb2 + ((size_t)((ks * 8 + j) * 64 + lane)) * 8);
                    P = __builtin_amdgcn_mfma_f32_16x16x32_bf16(ga[ks], bwf, P, 0, 0, 0);
                }
                #pragma unroll
                for (int rg = 0; rg < 4; rg++)
                    s_acc[j] += fmaxf(P[rg] + bias_j[j], 0.f);
            }
        }
    }

    // ---- per-wave partial -> own scratch; ONE barrier; block reduce
    {
        float* scratch = (float*)(arena + 4608);
        #pragma unroll
        for (int j = 0; j < 8; j++) {
            float v = s_acc[j];
            v += __shfl_xor(v, 16, 64);
            v += __shfl_xor(v, 32, 64);
            if (lane < 16) scratch[j * 16 + m] = v;
        }
    }
    __syncthreads();
    if (tid < 128) {
        float t = 0.f;
        #pragma unroll
        for (int w = 0; w < 4; w++)
            t += ((const float*)((unsigned short*)lds + w * 6720 + 4608))[tid];
        partials[(size_t)blockIdx.x * 128 + tid] = t;
    }
}

// ---------- kernel 5: mean over RT + FC ----------
__global__ __launch_bounds__(128) void fc_kernel(
    const float* __restrict__ partials, const float* __restrict__ fw,
    const float* __restrict__ fb, float* __restrict__ out)
{
    __shared__ float sm[128];
    const int b = blockIdx.x, tid = threadIdx.x;
    float s = 0.f;
    #pragma unroll
    for (int t = 0; t < 4; t++) s += partials[((b << 2) + t) * 128 + tid];
    sm[tid] = s * (1.0f / 512.0f);
    __syncthreads();
    if (tid < 64) {
        float acc = fb[tid];
        #pragma unroll 8
        for (int f = 0; f < 128; f++) acc += sm[f] * fw[f * 64 + tid];
        out[b * 64 + tid] = acc;
    }
}

extern "C" void kernel_launch(void* const* d_in, const int* in_sizes, int n_in,
                              void* d_out, int out_size, void* d_ws, size_t ws_size,
                              hipStream_t stream)
{
    const float* x   = (const float*)d_in[0];
    const float* w1  = (const float*)d_in[1];
    const float* b1  = (const float*)d_in[2];
    const float* w2  = (const float*)d_in[3];
    const float* b2  = (const float*)d_in[4];
    const float* g1w = (const float*)d_in[5];
    const float* g1b = (const float*)d_in[6];
    const float* g2w = (const float*)d_in[7];
    const float* g2b = (const float*)d_in[8];
    const float* fw  = (const float*)d_in[9];
    const float* fb  = (const float*)d_in[10];

    char* ws = (char*)d_ws;
    float* partials     = (float*)(ws);                           // [B][4][128] fp32 = 2MB
    unsigned short* Wb1 = (unsigned short*)(ws + 2097152);        // 4096 elems
    unsigned short* Wb2 = (unsigned short*)(ws + 2097152 + 16384);// 16384 elems
    unsigned short* Wc1 = (unsigned short*)(ws + 2097152 + 65536);// 1536 elems
    unsigned short* Wc2 = (unsigned short*)(ws + 2097152 + 81920);// 3072 elems
    float* out = (float*)d_out;

    repack_w<<<32, 256, 0, stream>>>(g1w, g2w, w1, w2, Wb1, Wb2, Wc1, Wc2);
    mega<<<NNODES / 128, 256, 0, stream>>>(x, Wc1, Wc2, Wb1, Wb2,
                                           b1, b2, g1b, g2b, partials);
    fc_kernel<<<B_, 128, 0, stream>>>(partials, fw, fb, out);
}

// Round 9
// 184.198 us; speedup vs baseline: 1.3780x; 1.3780x over previous
//
#include <hip/hip_runtime.h>
#include <hip/hip_bf16.h>

// Problem constants
#define B_      1024
#define CIN     9
#define T0_     2048
#define C1_     16
#define C2_     32
#define RT_     512
#define NNODES  (B_ * RT_)     // 524288
#define HID_    128
#define OUTF_   64

typedef __attribute__((ext_vector_type(8))) __bf16 bf16x8;
typedef __attribute__((ext_vector_type(4))) float f32x4;
typedef __attribute__((ext_vector_type(8))) unsigned short us8;

// ---------- helpers ----------
__device__ __forceinline__ float bf2f(unsigned short u) {
    union { unsigned int i; float f; } c; c.i = ((unsigned int)u) << 16; return c.f;
}
// round-half-up bf16 (2 ops)
__device__ __forceinline__ unsigned short f2bf1(float f) {
    union { float f; unsigned int i; } c; c.f = f;
    return (unsigned short)((c.i + 0x8000u) >> 16);
}
// packed pair: low short = bf16(lo), high short = bf16(hi); 2 adds + 1 v_perm
__device__ __forceinline__ unsigned int f2bf2(float lo, float hi) {
    union { float f; unsigned int i; } a, b; a.f = lo; b.f = hi;
    return __builtin_amdgcn_perm(b.i + 0x8000u, a.i + 0x8000u, 0x07060302u);
}
__device__ __forceinline__ float dinv_of(int r) {
    return (r == 0 || r == RT_ - 1) ? 0.70710678118f : 0.57735026919f;
}

// ---------- kernel R: repack all weights into bf16 MFMA fragment order (32 blocks) ----------
__global__ __launch_bounds__(256) void repack_w(
    const float* __restrict__ W1g, const float* __restrict__ W2g,
    const float* __restrict__ Wc1g, const float* __restrict__ Wc2g,
    unsigned short* __restrict__ Wb1, unsigned short* __restrict__ Wb2,
    unsigned short* __restrict__ Wc1, unsigned short* __restrict__ Wc2)
{
    const int tid = threadIdx.x;
    const int bid = blockIdx.x;
    if (bid < 8) {                                     // W1: 4096 elems, 512/block
        for (int i = tid; i < 512; i += 256) {
            int s = bid * 512 + i;
            int k = s >> 7, f = s & 127;
            int lane = ((k >> 3) << 4) + (f & 15);
            int e = (((f >> 4) * 64) + lane) * 8 + (k & 7);
            Wb1[e] = f2bf1(W1g[s]);
        }
    } else if (bid < 24) {                             // W2: 16384 elems, 1024/block
        for (int i = tid; i < 1024; i += 256) {
            int s = (bid - 8) * 1024 + i;
            int k = s >> 7, f = s & 127;
            int ks = k >> 5, lane = (((k >> 3) & 3) << 4) + (f & 15);
            int e = ((ks * 8 + (f >> 4)) * 64 + lane) * 8 + (k & 7);
            Wb2[e] = f2bf1(W2g[s]);
        }
    } else if (bid < 28) {                             // Wc1: 1536 elems, 384/block
        for (int i = tid; i < 384; i += 256) {
            int e = (bid - 24) * 384 + i;
            int j = e & 7, lane = (e >> 3) & 63, ks = e >> 9;
            int kk = ks * 32 + (lane >> 4) * 8 + j;
            int k = kk >> 4, ci = kk & 15, co = lane & 15;
            Wc1[e] = (k < 5 && ci < CIN) ? f2bf1(Wc1g[(co * CIN + ci) * 5 + k]) : 0;
        }
    } else {                                           // Wc2: 3072 elems, 768/block
        for (int i = tid; i < 768; i += 256) {
            int e = (bid - 28) * 768 + i;
            int j = e & 7, lane = (e >> 3) & 63, nt = (e >> 9) & 1, ks = e >> 10;
            int kk = ks * 32 + (lane >> 4) * 8 + j;
            int k = kk >> 4, ci = kk & 15, co = nt * 16 + (lane & 15);
            Wc2[e] = (k < 5) ? f2bf1(Wc2g[(co * C1_ + ci) * 5 + k]) : 0;
        }
    }
}

// ---------- MEGAKERNEL ----------
// R19 == R14 restored (best measured: mega 92.2us, total 182.8us).
// Quarter-major structure, node-major layouts, VALU stencils, 4 blocks/CU:
//  - per-quarter gcn2 reduction: acc complete after each quarter's G (full
//    K=128) -> acc2[2][2] (16 regs), reduced immediately
//  - E inside quarters: 34-row H slab per quarter
//  - biases from global (loop-invariant)
// Session evidence for stopping here: more occupancy (R14 vs R11: ~0), less
// VALU (R17: VALUBusy -9pts, time +10us), fewer barriers (R18: scheduler
// spills, +73us), MFMA-stencil (R13), slice-major (R12), wave-private (R18)
// all fail to beat this plateau. Latency-bound at ~72% combined issue under
// barrier-aligned phase chains; allocator blocks every higher-ILP variant.
//
// LDS overlay (bytes), all row strides 16B multiples:
//   xs    [0, 26496)       552*24 shorts   A,B
//   y1ext [26496, 39936)   280*24 shorts   B,C
//   y2loc [0, 10560)       132*40 shorts   C,D   (node-major)
//   As1   [10560, 22080)   144*40 shorts   D..E
//   Hq    [22080, 31328)   34*136 shorts   E,F (per-quarter slab)
//   A2q   [31328, 40032)   32*136 shorts   F,G (per-quarter)
__global__ __launch_bounds__(256, 4) void mega(
    const float* __restrict__ x,             // [B][9][2048] fp32
    const unsigned short* __restrict__ Wc1,  // conv1 B-frags
    const unsigned short* __restrict__ Wc2,  // conv2 B-frags
    const unsigned short* __restrict__ Wb1,  // gcn1 A-frags (W1^T)
    const unsigned short* __restrict__ Wb2,  // gcn2 B-frags
    const float* __restrict__ c1b, const float* __restrict__ c2b,
    const float* __restrict__ g1b, const float* __restrict__ g2b,
    float* __restrict__ partials)            // [B][4][128] fp32
{
    __shared__ __align__(16) unsigned char lds[40032];
    unsigned short* xs    = (unsigned short*)(lds);
    unsigned short* y1ext = (unsigned short*)(lds + 26496);
    unsigned short* y2loc = (unsigned short*)(lds);
    unsigned short* As1   = (unsigned short*)(lds + 10560);
    unsigned short* Hq    = (unsigned short*)(lds + 22080);
    unsigned short* A2q   = (unsigned short*)(lds + 31328);

    const int tid = threadIdx.x;
    const int b = blockIdx.x >> 2;
    const int r0 = (blockIdx.x & 3) * 128;

    const int lane = tid & 63, wave = tid >> 6;
    const int m = lane & 15, q = lane >> 4;
    const int ft0 = wave * 2;              // this wave's gcn1 output feat-tiles

    // prebuilt conv1 fragments: coalesced 16B loads
    bf16x8 wfB[3];
    #pragma unroll
    for (int ks = 0; ks < 3; ks++) wfB[ks] = *(const bf16x8*)(Wc1 + (ks * 64 + lane) * 8);

    // ---- phase A: stage x as bf16 time-major: xs[s][ci], s=0..551, xt=4r0-14+s
    {
        const float* xb = x + (size_t)b * CIN * T0_;
        const int xbase = 4 * r0 - 14;
        for (int s = tid; s < 552; s += 256) {
            const int xt = xbase + s;
            union { us8 v; unsigned int u[4]; } o0, o1;
            if (xt >= 0 && xt < T0_) {
                float xv[9];
                #pragma unroll
                for (int ci = 0; ci < 9; ci++) xv[ci] = xb[ci * T0_ + xt];
                o0.u[0] = f2bf2(xv[0], xv[1]); o0.u[1] = f2bf2(xv[2], xv[3]);
                o0.u[2] = f2bf2(xv[4], xv[5]); o0.u[3] = f2bf2(xv[6], xv[7]);
                o1.u[0] = f2bf2(xv[8], 0.f);   o1.u[1] = o1.u[2] = o1.u[3] = 0;
            } else {
                o0.u[0] = o0.u[1] = o0.u[2] = o0.u[3] = 0;
                o1.u[0] = o1.u[1] = o1.u[2] = o1.u[3] = 0;
            }
            *(us8*)(xs + s * 24) = o0.v;
            *(us8*)(xs + s * 24 + 8) = o1.v;
        }
    }
    // conv2 fragments loaded here: latency covered by phase A tail / barrier
    bf16x8 wfC[3][2];
    #pragma unroll
    for (int ks = 0; ks < 3; ks++)
        #pragma unroll
        for (int nt = 0; nt < 2; nt++)
            wfC[ks][nt] = *(const bf16x8*)(Wc2 + ((ks * 2 + nt) * 64 + lane) * 8);
    __syncthreads();

    // ---- phase B: conv1 MFMA + relu + pool -> y1ext (zero for t1 outside [0,1024))
    {
        const float bv = c1b[m];
        const int t1base = 2 * r0 - 6;
        for (int mt = wave; mt < 34; mt += 4) {
            f32x4 acc = {};
            #pragma unroll
            for (int ks = 0; ks < 3; ks++) {
                const int row = mt * 16 + m + ks * 2 + (q >> 1);
                const bf16x8 af = *(const bf16x8*)(xs + row * 24 + (q & 1) * 8);
                acc = __builtin_amdgcn_mfma_f32_16x16x32_bf16(af, wfB[ks], acc, 0, 0, 0);
            }
            const int prow = mt * 8 + q * 2;     // y1ext row; t1 = t1base + prow
            const int t1a = t1base + prow, t1b = t1a + 1;
            const float p0 = fmaxf(fmaxf(acc[0], acc[1]) + bv, 0.f);
            const float p1 = fmaxf(fmaxf(acc[2], acc[3]) + bv, 0.f);
            if (prow < 268)
                y1ext[prow * 24 + m] = (t1a >= 0 && t1a < 1024) ? f2bf1(p0) : (unsigned short)0;
            if (prow + 1 < 268)
                y1ext[(prow + 1) * 24 + m] = (t1b >= 0 && t1b < 1024) ? f2bf1(p1) : (unsigned short)0;
        }
        for (int idx = tid; idx < 288; idx += 256) y1ext[268 * 24 + idx] = 0;  // rows 268..279
    }
    __syncthreads();

    // ---- phase C: conv2 MFMA + relu + pool -> y2loc (132 nodes: r0-2 .. r0+129)
    {
        const float bv0 = c2b[m], bv1 = c2b[16 + m];
        for (int mt = wave; mt < 17; mt += 4) {
            f32x4 a0 = {}, a1 = {};
            #pragma unroll
            for (int ks = 0; ks < 3; ks++) {
                const int row = mt * 16 + m + ks * 2 + (q >> 1);
                const bf16x8 af = *(const bf16x8*)(y1ext + row * 24 + (q & 1) * 8);
                a0 = __builtin_amdgcn_mfma_f32_16x16x32_bf16(af, wfC[ks][0], a0, 0, 0, 0);
                a1 = __builtin_amdgcn_mfma_f32_16x16x32_bf16(af, wfC[ks][1], a1, 0, 0, 0);
            }
            const int nrow = mt * 8 + q * 2;
            if (nrow < 132) {
                y2loc[nrow * 40 + m]      = f2bf1(fmaxf(fmaxf(a0[0], a0[1]) + bv0, 0.f));
                y2loc[nrow * 40 + 16 + m] = f2bf1(fmaxf(fmaxf(a1[0], a1[1]) + bv1, 0.f));
            }
            if (nrow + 1 < 132) {
                y2loc[(nrow + 1) * 40 + m]      = f2bf1(fmaxf(fmaxf(a0[2], a0[3]) + bv0, 0.f));
                y2loc[(nrow + 1) * 40 + 16 + m] = f2bf1(fmaxf(fmaxf(a1[2], a1[3]) + bv1, 0.f));
            }
        }
    }
    // gcn1 A-frags (prebuilt, coalesced) while conv2 drains
    bf16x8 wfE[2];
    wfE[0] = *(const bf16x8*)(Wb1 + (ft0 * 64 + lane) * 8);
    wfE[1] = *(const bf16x8*)(Wb1 + ((ft0 + 1) * 64 + lane) * 8);
    __syncthreads();

    // ---- phase D (gcn1 aggregation, VALU stencil): As1 row i <-> node r0-1+i (i<130)
    for (int s = tid; s < 288; s += 256) {
        const int i = s >> 1, fh = (s & 1) * 16;
        unsigned short* dst = As1 + i * 40 + fh;
        const int r = r0 - 1 + i;
        union { us8 v; unsigned int u[4]; } o0, o1;
        if (i >= 130 || r < 0 || r >= RT_) {
            o0.u[0] = o0.u[1] = o0.u[2] = o0.u[3] = 0;
            o1.u[0] = o1.u[1] = o1.u[2] = o1.u[3] = 0;
        } else {
            const float dm = dinv_of(r), cm = dm * dm;
            const unsigned short* Yc = y2loc + (i + 1) * 40 + fh;
            us8 c0 = *(const us8*)(Yc), c1 = *(const us8*)(Yc + 8);
            float v[16];
            #pragma unroll
            for (int j = 0; j < 8; j++) { v[j] = cm * bf2f(c0[j]); v[8 + j] = cm * bf2f(c1[j]); }
            if (r > 0) {
                const float cl = dm * dinv_of(r - 1);
                us8 a0 = *(const us8*)(Yc - 40), a1 = *(const us8*)(Yc - 32);
                #pragma unroll
                for (int j = 0; j < 8; j++) { v[j] += cl * bf2f(a0[j]); v[8 + j] += cl * bf2f(a1[j]); }
            }
            if (r < RT_ - 1) {
                const float cr = dm * dinv_of(r + 1);
                us8 a0 = *(const us8*)(Yc + 40), a1 = *(const us8*)(Yc + 48);
                #pragma unroll
                for (int j = 0; j < 8; j++) { v[j] += cr * bf2f(a0[j]); v[8 + j] += cr * bf2f(a1[j]); }
            }
            #pragma unroll
            for (int i2 = 0; i2 < 4; i2++) {
                o0.u[i2] = f2bf2(v[2 * i2], v[2 * i2 + 1]);
                o1.u[i2] = f2bf2(v[8 + 2 * i2], v[9 + 2 * i2]);
            }
        }
        *(us8*)dst = o0.v; *(us8*)(dst + 8) = o1.v;
    }
    // gcn2 B-frags (prebuilt, coalesced) during phase D
    bf16x8 bw[4][2];
    #pragma unroll
    for (int ks = 0; ks < 4; ks++)
        #pragma unroll
        for (int i = 0; i < 2; i++)
            bw[ks][i] = *(const bf16x8*)(Wb2 + ((size_t)((ks * 8 + wave * 2 + i) * 64 + lane)) * 8);
    // biases from global (loop-invariant; L2-resident): no LDS needed
    const float4 bv0 = *(const float4*)&g1b[ft0 * 16 + q * 4];
    const float4 bv1 = *(const float4*)&g1b[(ft0 + 1) * 16 + q * 4];
    const float bb0 = g2b[wave * 32 + m];
    const float bb1 = g2b[wave * 32 + 16 + m];
    __syncthreads();

    const f32x4 zz = {};

    // E(qi): H slab rows 0..33 <-> nodes r0+qi*32-1 .. r0+qi*32+32, from As1 rows
    // qi*32 .. qi*32+47 (tiles of 16, rows >=34 masked). Halo rows at sample
    // edges hold relu(b1) garbage; F zeroes them via cl/cr coefficients.
    auto do_E = [&](int qi) {
        #pragma unroll
        for (int nt = 0; nt < 3; nt++) {
            const bf16x8 bfr = *(const bf16x8*)(As1 + (qi * 32 + nt * 16 + m) * 40 + q * 8);
            f32x4 o0 = __builtin_amdgcn_mfma_f32_16x16x32_bf16(wfE[0], bfr, zz, 0, 0, 0);
            f32x4 o1 = __builtin_amdgcn_mfma_f32_16x16x32_bf16(wfE[1], bfr, zz, 0, 0, 0);
            const int hrow = nt * 16 + m;
            if (hrow < 34) {
                union { ushort4 s; unsigned int u[2]; } w0, w1;
                w0.u[0] = f2bf2(fmaxf(o0[0] + bv0.x, 0.f), fmaxf(o0[1] + bv0.y, 0.f));
                w0.u[1] = f2bf2(fmaxf(o0[2] + bv0.z, 0.f), fmaxf(o0[3] + bv0.w, 0.f));
                w1.u[0] = f2bf2(fmaxf(o1[0] + bv1.x, 0.f), fmaxf(o1[1] + bv1.y, 0.f));
                w1.u[1] = f2bf2(fmaxf(o1[2] + bv1.z, 0.f), fmaxf(o1[3] + bv1.w, 0.f));
                *(ushort4*)(Hq + hrow * 136 + ft0 * 16 + q * 4) = w0.s;
                *(ushort4*)(Hq + hrow * 136 + (ft0 + 1) * 16 + q * 4) = w1.s;
            }
        }
    };

    do_E(0);
    __syncthreads();

    float s0 = 0.f, s1 = 0.f;
    for (int qi = 0; qi < 4; qi++) {
        // F(qi): VALU stencil Hq -> A2q (32 nodes x 128 feats)
        {
            const int jl = tid >> 3, fh = (tid & 7) * 16;
            const int r = r0 + qi * 32 + jl;
            const float dm = dinv_of(r), cm = dm * dm;
            const float cl = (r > 0) ? dm * dinv_of(r - 1) : 0.f;
            const float cr = (r < RT_ - 1) ? dm * dinv_of(r + 1) : 0.f;
            const unsigned short* Hl = Hq + jl * 136 + fh;
            const unsigned short* Hc = Hl + 136;
            const unsigned short* Hr = Hc + 136;
            unsigned short* dst = A2q + jl * 136 + fh;
            #pragma unroll
            for (int c = 0; c < 2; c++) {
                us8 cc = *(const us8*)(Hc + c * 8);
                us8 ll = *(const us8*)(Hl + c * 8);
                us8 rr = *(const us8*)(Hr + c * 8);
                float v[8];
                #pragma unroll
                for (int e = 0; e < 8; e++)
                    v[e] = cm * bf2f(cc[e]) + cl * bf2f(ll[e]) + cr * bf2f(rr[e]);
                union { us8 v; unsigned int u[4]; } o;
                #pragma unroll
                for (int i2 = 0; i2 < 4; i2++) o.u[i2] = f2bf2(v[2 * i2], v[2 * i2 + 1]);
                *(us8*)(dst + c * 8) = o.v;
            }
        }
        __syncthreads();

        // G(qi): gcn2 for this quarter's 2 node-tiles, FULL K=128 -> acc complete;
        // reduce immediately (acc never persists across quarters)
        {
            f32x4 acc2[2][2] = {};
            #pragma unroll
            for (int ntl = 0; ntl < 2; ntl++)
                #pragma unroll
                for (int ks = 0; ks < 4; ks++) {
                    const bf16x8 af = *(const bf16x8*)(A2q + (ntl * 16 + m) * 136 + ks * 32 + q * 8);
                    acc2[ntl][0] = __builtin_amdgcn_mfma_f32_16x16x32_bf16(af, bw[ks][0], acc2[ntl][0], 0, 0, 0);
                    acc2[ntl][1] = __builtin_amdgcn_mfma_f32_16x16x32_bf16(af, bw[ks][1], acc2[ntl][1], 0, 0, 0);
                }
            #pragma unroll
            for (int ntl = 0; ntl < 2; ntl++)
                #pragma unroll
                for (int rgi = 0; rgi < 4; rgi++) {
                    s0 += fmaxf(acc2[ntl][0][rgi] + bb0, 0.f);
                    s1 += fmaxf(acc2[ntl][1][rgi] + bb1, 0.f);
                }
        }
        // E(qi+1) shares this barrier interval with G (disjoint LDS: Hq vs A2q)
        if (qi < 3) {
            do_E(qi + 1);
            __syncthreads();
        }
    }

    // ---- epilogue: wave-reduce column sums, plain stores (no atomics)
    {
        s0 += __shfl_xor(s0, 16, 64); s0 += __shfl_xor(s0, 32, 64);
        s1 += __shfl_xor(s1, 16, 64); s1 += __shfl_xor(s1, 32, 64);
        if (lane < 16) {
            float* p = partials + (size_t)blockIdx.x * 128 + wave * 32;
            p[m] = s0;
            p[16 + m] = s1;
        }
    }
}

// ---------- kernel 5: mean over RT + FC ----------
__global__ __launch_bounds__(128) void fc_kernel(
    const float* __restrict__ partials, const float* __restrict__ fw,
    const float* __restrict__ fb, float* __restrict__ out)
{
    __shared__ float sm[128];
    const int b = blockIdx.x, tid = threadIdx.x;
    float s = 0.f;
    #pragma unroll
    for (int t = 0; t < 4; t++) s += partials[((b << 2) + t) * 128 + tid];
    sm[tid] = s * (1.0f / 512.0f);
    __syncthreads();
    if (tid < 64) {
        float acc = fb[tid];
        #pragma unroll 8
        for (int f = 0; f < 128; f++) acc += sm[f] * fw[f * 64 + tid];
        out[b * 64 + tid] = acc;
    }
}

extern "C" void kernel_launch(void* const* d_in, const int* in_sizes, int n_in,
                              void* d_out, int out_size, void* d_ws, size_t ws_size,
                              hipStream_t stream)
{
    const float* x   = (const float*)d_in[0];
    const float* w1  = (const float*)d_in[1];
    const float* b1  = (const float*)d_in[2];
    const float* w2  = (const float*)d_in[3];
    const float* b2  = (const float*)d_in[4];
    const float* g1w = (const float*)d_in[5];
    const float* g1b = (const float*)d_in[6];
    const float* g2w = (const float*)d_in[7];
    const float* g2b = (const float*)d_in[8];
    const float* fw  = (const float*)d_in[9];
    const float* fb  = (const float*)d_in[10];

    char* ws = (char*)d_ws;
    float* partials     = (float*)(ws);                           // [B][4][128] fp32 = 2MB
    unsigned short* Wb1 = (unsigned short*)(ws + 2097152);        // 4096 elems
    unsigned short* Wb2 = (unsigned short*)(ws + 2097152 + 16384);// 16384 elems
    unsigned short* Wc1 = (unsigned short*)(ws + 2097152 + 65536);// 1536 elems
    unsigned short* Wc2 = (unsigned short*)(ws + 2097152 + 81920);// 3072 elems
    float* out = (float*)d_out;

    repack_w<<<32, 256, 0, stream>>>(g1w, g2w, w1, w2, Wb1, Wb2, Wc1, Wc2);
    mega<<<NNODES / 128, 256, 0, stream>>>(x, Wc1, Wc2, Wb1, Wb2,
                                           b1, b2, g1b, g2b, partials);
    fc_kernel<<<B_, 128, 0, stream>>>(partials, fw, fb, out);
}